// Round 9
// baseline (1284.717 us; speedup 1.0000x reference)
//
#include <hip/hip_runtime.h>
#include <math.h>

// ---------------------------------------------------------------------------
// SpatialGNN: 3x GCN (residual) + 4-head GAT + MLP + log_softmax
// N=100000, E=1600000, IN=8, HID=64, HEADS=4, OUT=3
//
// R19 changes vs R18 (513.9us, gat_agg 81us issue-bound):
//  - scan_pass3 additionally partitions nodes into short (deg<=15) / long
//    lists (2 atomic cursors) for degree-specialized GAT kernels.
//  - gat_agg_short: TWO nodes per wave share one 16x16x32 MFMA tile:
//    node A weights in A-rows 0-7 / k 0-15, node B in rows 8-15 / k 16-31
//    (static zero quadrants -> no cross terms). C rows 0-7 = A, 8-15 = B.
//    Halves per-short-node cost (staging, gather, B-reads are per-pair).
//  - dh denominators via ones-MFMA (B=1 splat): acc4[r] = sum_k A[r][k]
//    = sum of weights per head; replaces 4x red32 trees in BOTH paths.
//  - gat_agg_long: R18 long path + list-driven + ones-MFMA dh + red32max.
//  - everything else byte-identical to R18.
// ---------------------------------------------------------------------------

typedef _Float16 half8 __attribute__((ext_vector_type(8)));
typedef _Float16 f16x8 __attribute__((ext_vector_type(8)));
typedef float f32x4 __attribute__((ext_vector_type(4)));

__device__ __forceinline__ float leaky02(float v) { return v > 0.f ? v : 0.2f * v; }

// ---- cross-lane reduction helpers (DPP/swizzle; minimize DS-pipe ops) -----

template <int CTRL>
__device__ __forceinline__ float dpp_add(float v) {
    int iv = __builtin_bit_cast(int, v);
    int r = __builtin_amdgcn_update_dpp(iv, iv, CTRL, 0xF, 0xF, false);
    return v + __builtin_bit_cast(float, r);
}
template <int OFF>
__device__ __forceinline__ float swz_add(float v) {
    int r = __builtin_amdgcn_ds_swizzle(__builtin_bit_cast(int, v), OFF);
    return v + __builtin_bit_cast(float, r);
}
template <int CTRL>
__device__ __forceinline__ float dpp_max(float v) {
    int iv = __builtin_bit_cast(int, v);
    int r = __builtin_amdgcn_update_dpp(iv, iv, CTRL, 0xF, 0xF, false);
    return fmaxf(v, __builtin_bit_cast(float, r));
}
template <int OFF>
__device__ __forceinline__ float swz_max(float v) {
    int r = __builtin_amdgcn_ds_swizzle(__builtin_bit_cast(int, v), OFF);
    return fmaxf(v, __builtin_bit_cast(float, r));
}
__device__ __forceinline__ float red8(float v) {
    v = dpp_add<0xB1>(v);     // xor1
    v = dpp_add<0x4E>(v);     // xor2
    v = swz_add<0x101F>(v);   // xor4
    return v;
}
__device__ __forceinline__ float red16(float v) {
    v = dpp_add<0xB1>(v);
    v = dpp_add<0x4E>(v);
    v = swz_add<0x101F>(v);
    v = dpp_add<0x128>(v);    // row_ror:8 -> completes 16-lane sum
    return v;
}
__device__ __forceinline__ float red16max(float v) {   // max within 16-lane group
    v = dpp_max<0xB1>(v);
    v = dpp_max<0x4E>(v);
    v = swz_max<0x101F>(v);
    v = dpp_max<0x128>(v);
    return v;
}
__device__ __forceinline__ float red64(float v) {
    v = dpp_add<0xB1>(v);
    v = dpp_add<0x4E>(v);
    v = swz_add<0x101F>(v);
    v = dpp_add<0x128>(v);    // xor8: row_ror:8
    v = swz_add<0x401F>(v);   // xor16
    v = v + __shfl_xor(v, 32);
    return v;
}
__device__ __forceinline__ float red32max(float v) {   // max within each 32-lane half
    v = dpp_max<0xB1>(v);
    v = dpp_max<0x4E>(v);
    v = swz_max<0x101F>(v);
    v = dpp_max<0x128>(v);
    v = swz_max<0x401F>(v);
    return v;
}

// ---- CSR build ------------------------------------------------------------

// XCD-range-filtered count: group blockIdx&7 counts only its dst range.
__global__ void count_kernel(const int* __restrict__ dst, int E, int range,
                             int* __restrict__ counts) {
    int grp = blockIdx.x & 7;
    int nlo = grp * range;
    int nhi = nlo + range;
    int nblk = gridDim.x >> 3;
    int c = blockIdx.x >> 3;
    int stride = nblk * blockDim.x;
    for (int e = c * blockDim.x + threadIdx.x; e < E; e += stride) {
        int d = dst[e];
        if (d >= nlo && d < nhi) atomicAdd(&counts[d], 1);
    }
}

__global__ void scan_pass1(const int* __restrict__ counts, int n, int* __restrict__ blockSums) {
    __shared__ int sh[256];
    int base = blockIdx.x * 2048;
    int tid = threadIdx.x;
    int s = 0;
#pragma unroll
    for (int j = 0; j < 8; ++j) {
        int idx = base + tid * 8 + j;
        if (idx < n) s += counts[idx];
    }
    sh[tid] = s;
    __syncthreads();
    for (int off = 128; off > 0; off >>= 1) {
        if (tid < off) sh[tid] += sh[tid + off];
        __syncthreads();
    }
    if (tid == 0) blockSums[blockIdx.x] = sh[0];
}

__global__ void scan_pass2(const int* __restrict__ blockSums, int nb, int* __restrict__ blockOffs) {
    if (threadIdx.x == 0 && blockIdx.x == 0) {
        int run = 0;
        for (int i = 0; i < nb; ++i) { blockOffs[i] = run; run += blockSums[i]; }
    }
}

__global__ void scan_pass3(const int* __restrict__ counts, int n,
                           const int* __restrict__ blockOffs,
                           const float* __restrict__ x,
                           int* __restrict__ row_ptr, int* __restrict__ cursor,
                           float* __restrict__ dinv, float* __restrict__ rdinv,
                           _Float16* __restrict__ xs,
                           int* __restrict__ shortList, int* __restrict__ longList,
                           int* __restrict__ nodeCnts) {
    __shared__ int sh[256];
    int base = blockIdx.x * 2048;
    int tid = threadIdx.x;
    int cnt[8];
    int local = 0;
#pragma unroll
    for (int j = 0; j < 8; ++j) {
        int idx = base + tid * 8 + j;
        cnt[j] = (idx < n) ? counts[idx] : 0;
        local += cnt[j];
    }
    sh[tid] = local;
    __syncthreads();
    for (int off = 1; off < 256; off <<= 1) {
        int v = (tid >= off) ? sh[tid - off] : 0;
        __syncthreads();
        sh[tid] += v;
        __syncthreads();
    }
    int run = blockOffs[blockIdx.x] + sh[tid] - local;
#pragma unroll
    for (int j = 0; j < 8; ++j) {
        int idx = base + tid * 8 + j;
        if (idx < n) {
            row_ptr[idx] = run;
            cursor[idx] = run;
            float dv = rsqrtf((float)(cnt[j] + 1));
            dinv[idx] = dv;
            rdinv[idx] = sqrtf((float)(cnt[j] + 1));
#pragma unroll
            for (int t = 0; t < 8; ++t) xs[idx * 8 + t] = (_Float16)(dv * x[idx * 8 + t]);
            // degree partition for GAT kernels: short = nslots(deg+1) <= 16
            int isS = (cnt[j] <= 15) ? 0 : 1;
            int p = atomicAdd(&nodeCnts[isS], 1);
            if (isS == 0) shortList[p] = idx; else longList[p] = idx;
            run += cnt[j];
            if (idx == n - 1) row_ptr[n] = run;
        }
    }
}

// XCD-range-filtered scatter (R9, kept): col_src/cursor writes stay XCD-local.
__global__ void scatter_kernel(const int* __restrict__ src, const int* __restrict__ dst,
                               int E, int range,
                               int* __restrict__ cursor, int* __restrict__ col_src) {
    int grp = blockIdx.x & 7;
    int nlo = grp * range;
    int nhi = nlo + range;
    int nblk = gridDim.x >> 3;
    int c = blockIdx.x >> 3;
    int stride = nblk * blockDim.x;
    for (int e = c * blockDim.x + threadIdx.x; e < E; e += stride) {
        int d = dst[e];
        if (d >= nlo && d < nhi) {
            int pos = atomicAdd(&cursor[d], 1);
            col_src[pos] = src[e];
        }
    }
}

// ---- weight precompute: Ccomb + W2P/W3P (fp16 split, B-frag order) --------
// B-frag packing (validated by mlp_mfma): for k index i, out-ch j:
//   kt = i>>5, l = (((i>>3)&3)<<4)|(j&15), e = i&7, ct = j>>4.

__global__ void ccomb_kernel(const float* __restrict__ Wg, const float* __restrict__ bg,
                             const float* __restrict__ wc1, const float* __restrict__ bc1,
                             const float* __restrict__ att_src, const float* __restrict__ att_dst,
                             const float* __restrict__ w2, const float* __restrict__ w3,
                             _Float16* __restrict__ CcombP, float* __restrict__ bcomb,
                             float* __restrict__ wse, float* __restrict__ wde,
                             _Float16* __restrict__ W2P, _Float16* __restrict__ W3P) {
    int bid = blockIdx.x;   // 0..384
    int j = threadIdx.x;    // 64 threads
    if (bid < 256) {
        int i = bid;        // k index (agg channel)
        float s = 0.f;
        for (int c = 0; c < 64; ++c)
            s += Wg[(i & 63) * 256 + (i >> 6) * 64 + c] * wc1[((i >> 6) * 64 + c) * 64 + j];
        _Float16 hi = (_Float16)s;
        _Float16 lo = (_Float16)(s - (float)hi);
        int kt = i >> 5, l = (((i >> 3) & 3) << 4) | (j & 15), e = i & 7, ct = j >> 4;
        CcombP[(ct * 8 + kt) * 512 + l * 8 + e] = hi;
        CcombP[(32 + ct * 8 + kt) * 512 + l * 8 + e] = lo;
    } else if (bid == 256) {
        float s = bc1[j];
        for (int i = 0; i < 256; ++i) s += bg[i] * wc1[i * 64 + j];
        bcomb[j] = s;
#pragma unroll
        for (int h = 0; h < 4; ++h) {
            float ss = 0.f, sd = 0.f;
            for (int c = 0; c < 64; ++c) {
                float w = Wg[j * 256 + h * 64 + c];
                ss += w * att_src[h * 64 + c];
                sd += w * att_dst[h * 64 + c];
            }
            wse[j * 4 + h] = ss;
            wde[j * 4 + h] = sd;
        }
    } else {
        // W2P / W3P: K=64, 8 frags (ct*2+kt) hi + 8 lo
        int i = (bid < 321) ? (bid - 257) : (bid - 321);
        const float* W = (bid < 321) ? w2 : w3;
        _Float16* WP = (bid < 321) ? W2P : W3P;
        float s = W[i * 64 + j];
        _Float16 hi = (_Float16)s;
        _Float16 lo = (_Float16)(s - (float)hi);
        int kt = i >> 5, l = (((i >> 3) & 3) << 4) | (j & 15), e = i & 7, ct = j >> 4;
        WP[(ct * 2 + kt) * 512 + l * 8 + e] = hi;
        WP[(8 + ct * 2 + kt) * 512 + l * 8 + e] = lo;
    }
}

// ---- GCN layer 1: one edge per lane (16B half8 row) -----------------------

__global__ void gcn_layer1(const half8* __restrict__ xs8,
                           const float* __restrict__ W1, const float* __restrict__ b1,
                           const int* __restrict__ row_ptr, const int* __restrict__ col_src,
                           const float* __restrict__ dinv, int n,
                           _Float16* __restrict__ hs1) {
    int tid = threadIdx.x, lane = tid & 63, wid = tid >> 6;
    int node = blockIdx.x * 4 + wid;
    if (node >= n) return;
    int beg = row_ptr[node], end = row_ptr[node + 1];
    int deg = end - beg;
    float acc[8] = {0.f, 0.f, 0.f, 0.f, 0.f, 0.f, 0.f, 0.f};
    for (int base = 0; base < deg; base += 64) {
        int cs = col_src[min(beg + base + lane, end - 1)];
        half8 v = xs8[cs];
        if (base + lane < deg) {
#pragma unroll
            for (int c = 0; c < 8; ++c) acc[c] += (float)v[c];
        }
    }
#pragma unroll
    for (int c = 0; c < 8; ++c) acc[c] = red64(acc[c]);
    half8 sv = xs8[node];
    float di = dinv[node];
    float agg[8];
#pragma unroll
    for (int c = 0; c < 8; ++c) agg[c] = (acc[c] + (float)sv[c]) * di;
    float sum = b1[lane];
#pragma unroll
    for (int k = 0; k < 8; ++k) sum = fmaf(agg[k], W1[k * 64 + lane], sum);
    hs1[node * 64 + lane] = (_Float16)(di * fmaxf(sum, 0.f));
}

// ---- GCN aggregation: gather + red8 + dinv -> fp16 agg rows ---------------

__global__ void gcn_agg(const _Float16* __restrict__ hs_in,
                        const int* __restrict__ row_ptr, const int* __restrict__ col_src,
                        const float* __restrict__ dinv, int n,
                        _Float16* __restrict__ aggout) {
    int tid = threadIdx.x, lane = tid & 63, wid = tid >> 6;
    int node = blockIdx.x * 4 + wid;
    if (node >= n) return;
    int t = lane >> 3, g = lane & 7;
    const half8* hs8 = (const half8*)hs_in;
    int beg = row_ptr[node], end = row_ptr[node + 1];
    int deg = end - beg;
    half8 sv = hs8[node * 8 + t];
    float ac[8];
#pragma unroll
    for (int c = 0; c < 8; ++c) ac[c] = (g == 0) ? (float)sv[c] : 0.f;
    for (int base = 0; base < deg; base += 64) {
        int cs = col_src[min(beg + base + lane, end - 1)];
        int lim = min(deg - base, 64);
        auto bodyF = [&](int eo8) {
            int s = __shfl(cs, eo8 + g);
            half8 v = hs8[s * 8 + t];
#pragma unroll
            for (int c = 0; c < 8; ++c) ac[c] += (float)v[c];
        };
        auto bodyG = [&](int eo8) {
            int eo = eo8 + g;
            int s = __shfl(cs, eo);
            half8 v = hs8[s * 8 + t];
            if (eo < lim) {
#pragma unroll
                for (int c = 0; c < 8; ++c) ac[c] += (float)v[c];
            }
        };
        int eo8 = 0;
        for (; eo8 + 16 <= lim; eo8 += 16) { bodyF(eo8); bodyF(eo8 + 8); }
        if (eo8 < lim) {
            bodyG(eo8);
            eo8 += 8;
            if (eo8 < lim) bodyG(eo8);
        }
    }
    float di = dinv[node];
#pragma unroll
    for (int c = 0; c < 8; ++c) ac[c] = red8(ac[c]) * di;
    if (g == 0) {
        half8 hv;
#pragma unroll
        for (int c = 0; c < 8; ++c) hv[c] = (_Float16)ac[c];
        *(half8*)(aggout + (size_t)node * 64 + t * 8) = hv;
    }
}

// ---- GCN transform on matrix cores: Z = relu(agg @ W + b), residual -------

template <bool LAST>
__global__ __launch_bounds__(256) void gcn_mfma(
        const _Float16* __restrict__ agg,
        const _Float16* __restrict__ WP,
        const float* __restrict__ b,
        const _Float16* __restrict__ hs_in,
        const float* __restrict__ dinv, const float* __restrict__ rdinv,
        const float* __restrict__ wse, const float* __restrict__ wde,
        int n, _Float16* __restrict__ hout,
        float4* __restrict__ a_src4, float4* __restrict__ a_dst4) {
    __shared__ float partS[4][16][4];
    __shared__ float partD[4][16][4];
    int tid = threadIdx.x;
    int lane = tid & 63;
    int w = __builtin_amdgcn_readfirstlane(tid >> 6);   // ct slice
    int c16 = lane & 15, hi = lane >> 4;

    f16x8 bh[2], blo[2];
#pragma unroll
    for (int kt = 0; kt < 2; ++kt) {
        bh[kt]  = *(const f16x8*)(WP + (size_t)(w * 2 + kt) * 512 + lane * 8);
        blo[kt] = *(const f16x8*)(WP + (size_t)(8 + w * 2 + kt) * 512 + lane * 8);
    }
    int col = w * 16 + c16;
    float bl = b[col];
    float4 wev, wdv;
    if (LAST) {
        wev = ((const float4*)wse)[col];
        wdv = ((const float4*)wde)[col];
    }

    int ntiles = (n + 15) >> 4;
    for (int tile = blockIdx.x; tile < ntiles; tile += gridDim.x) {
        int rowb = tile * 16;
        int arow = min(rowb + c16, n - 1);
        const _Float16* ap = agg + (size_t)arow * 64 + hi * 8;
        f16x8 a0 = *(const f16x8*)(ap);
        f16x8 a1 = *(const f16x8*)(ap + 32);
        f32x4 acc = {0.f, 0.f, 0.f, 0.f};
        acc = __builtin_amdgcn_mfma_f32_16x16x32_f16(a0, bh[0],  acc, 0, 0, 0);
        acc = __builtin_amdgcn_mfma_f32_16x16x32_f16(a0, blo[0], acc, 0, 0, 0);
        acc = __builtin_amdgcn_mfma_f32_16x16x32_f16(a1, bh[1],  acc, 0, 0, 0);
        acc = __builtin_amdgcn_mfma_f32_16x16x32_f16(a1, blo[1], acc, 0, 0, 0);
#pragma unroll
        for (int r = 0; r < 4; ++r) {
            int noder = rowb + hi * 4 + r;
            bool ok = noder < n;
            int ni = min(noder, n - 1);
            float hp = rdinv[ni] * (float)hs_in[(size_t)ni * 64 + col];
            float z = fmaxf(acc[r] + bl, 0.f);
            float hv = hp + z;
            if (!LAST) {
                if (ok) hout[(size_t)ni * 64 + col] = (_Float16)(dinv[ni] * hv);
            } else {
                if (ok) hout[(size_t)ni * 64 + col] = (_Float16)hv;
                float s0 = red16(hv * wev.x), s1 = red16(hv * wev.y);
                float s2 = red16(hv * wev.z), s3 = red16(hv * wev.w);
                float d0 = red16(hv * wdv.x), d1 = red16(hv * wdv.y);
                float d2 = red16(hv * wdv.z), d3 = red16(hv * wdv.w);
                if (c16 == 0) {
                    *(float4*)&partS[w][hi * 4 + r][0] = make_float4(s0, s1, s2, s3);
                    *(float4*)&partD[w][hi * 4 + r][0] = make_float4(d0, d1, d2, d3);
                }
            }
        }
        if (LAST) {
            __syncthreads();
            if (tid < 16) {
                int node = rowb + tid;
                if (node < n) {
                    float4 s = make_float4(
                        partS[0][tid][0] + partS[1][tid][0] + partS[2][tid][0] + partS[3][tid][0],
                        partS[0][tid][1] + partS[1][tid][1] + partS[2][tid][1] + partS[3][tid][1],
                        partS[0][tid][2] + partS[1][tid][2] + partS[2][tid][2] + partS[3][tid][2],
                        partS[0][tid][3] + partS[1][tid][3] + partS[2][tid][3] + partS[3][tid][3]);
                    float4 d = make_float4(
                        partD[0][tid][0] + partD[1][tid][0] + partD[2][tid][0] + partD[3][tid][0],
                        partD[0][tid][1] + partD[1][tid][1] + partD[2][tid][1] + partD[3][tid][1],
                        partD[0][tid][2] + partD[1][tid][2] + partD[2][tid][2] + partD[3][tid][2],
                        partD[0][tid][3] + partD[1][tid][3] + partD[2][tid][3] + partD[3][tid][3]);
                    a_src4[node] = s;
                    a_dst4[node] = d;
                }
            }
            __syncthreads();
        }
    }
}

// ---- GAT aggregate: short kernel (2 nodes per wave, one K=32 MFMA tile) ---
//
// wAT [m][k] stride 40: rows 0-3 = node A hi heads (k 0-15 live), rows 4-7 =
// A lo; rows 8-11 = node B hi (k 16-31 live), 12-15 = B lo. Dead quadrants
// zeroed once. Hs [32][72] XOR-swizzled: rows 0-15 = A sources, 16-31 = B.
// One 16x16x32 MFMA per channel fragment + one ones-MFMA for denominators.
// C rows 0-7 = node A (hi+lo via shfl_xor16), rows 8-15 = node B.

__global__ __launch_bounds__(256, 4) void gat_agg_short(
        const _Float16* __restrict__ h3,
        const float4* __restrict__ a_src4, const float4* __restrict__ a_dst4,
        const int* __restrict__ row_ptr, const int* __restrict__ col_src,
        const int* __restrict__ shortList, const int* __restrict__ nodeCnts,
        _Float16* __restrict__ aggout) {
    __shared__ _Float16 HsAll[4][32 * 72];
    __shared__ _Float16 wATAll[4][16 * 40];
    int tid = threadIdx.x, lane = tid & 63, wid = tid >> 6;
    int nshort = nodeCnts[0];
    int i0 = (blockIdx.x * 4 + wid) * 2;
    if (i0 >= nshort) return;
    int nodeA = shortList[i0];
    int nodeB = (i0 + 1 < nshort) ? shortList[i0 + 1] : nodeA;
    _Float16* Hs = HsAll[wid];
    _Float16* wAT = wATAll[wid];

    // zero dead quadrants: rows 0-7 cols 16-31, rows 8-15 cols 0-15
    {
        int zm = lane >> 2;
        int zc = ((zm < 8) ? 16 : 0) + (lane & 3) * 4;
#pragma unroll
        for (int j = 0; j < 4; ++j) wAT[zm * 40 + zc + j] = (_Float16)0.f;
    }

    int q = lane >> 4, m16 = lane & 15;
    int c0 = (lane & 7) * 8;
    int sl16 = lane & 15;
    int myNode = (lane < 16) ? nodeA : ((lane < 32) ? nodeB : nodeA);
    int begL = row_ptr[myNode], endL = row_ptr[myNode + 1];
    int nslL = endL - begL + 1;
    float4 adv = a_dst4[myNode];
    int eidx = max(min(begL + sl16 - 1, endL - 1), 0);
    int cs = (sl16 == 0) ? myNode : col_src[eidx];
    float4 as = a_src4[cs];
    float vm = (sl16 < nslL && lane < 32) ? 1.f : 0.f;
    float l0 = leaky02(as.x + adv.x);
    float l1 = leaky02(as.y + adv.y);
    float l2 = leaky02(as.z + adv.z);
    float l3 = leaky02(as.w + adv.w);
    float m0 = red16max(vm > 0.f ? l0 : -1e30f);
    float m1 = red16max(vm > 0.f ? l1 : -1e30f);
    float m2 = red16max(vm > 0.f ? l2 : -1e30f);
    float m3 = red16max(vm > 0.f ? l3 : -1e30f);
    float w0 = vm * __expf(fminf(l0 - m0, 10.f));
    float w1 = vm * __expf(fminf(l1 - m1, 10.f));
    float w2 = vm * __expf(fminf(l2 - m2, 10.f));
    float w3 = vm * __expf(fminf(l3 - m3, 10.f));
    if (lane < 32) {
        int rb = (lane < 16) ? 0 : 8;          // node A rows 0-7, B rows 8-15
        int k = lane;                          // A: k 0-15, B: k 16-31
        _Float16 h0 = (_Float16)w0, h1 = (_Float16)w1;
        _Float16 h2 = (_Float16)w2, h3v = (_Float16)w3;
        wAT[(rb + 0) * 40 + k] = h0;
        wAT[(rb + 1) * 40 + k] = h1;
        wAT[(rb + 2) * 40 + k] = h2;
        wAT[(rb + 3) * 40 + k] = h3v;
        wAT[(rb + 4) * 40 + k] = (_Float16)(w0 - (float)h0);
        wAT[(rb + 5) * 40 + k] = (_Float16)(w1 - (float)h1);
        wAT[(rb + 6) * 40 + k] = (_Float16)(w2 - (float)h2);
        wAT[(rb + 7) * 40 + k] = (_Float16)(w3 - (float)h3v);
    }
    // H gather: rows 0-15 node A sources, 16-31 node B (cs lanes 0-31)
#pragma unroll
    for (int i = 0; i < 4; ++i) {
        int r = i * 8 + (lane >> 3);
        int s = __shfl(cs, r);
        half8 hv = *(const half8*)(h3 + (size_t)s * 64 + c0);
        *(half8*)(Hs + r * 72 + (c0 ^ (i << 4))) = hv;
    }
    __asm__ volatile("s_waitcnt lgkmcnt(0)" ::: "memory");
    f16x8 A = *(const f16x8*)(wAT + m16 * 40 + q * 8);
    int swz = q << 4;
    const _Float16* Bb0 = Hs + (size_t)q * 8 * 72 + ((0 * 16 + m16) ^ swz);
    const _Float16* Bb1 = Hs + (size_t)q * 8 * 72 + ((1 * 16 + m16) ^ swz);
    const _Float16* Bb2 = Hs + (size_t)q * 8 * 72 + ((2 * 16 + m16) ^ swz);
    const _Float16* Bb3 = Hs + (size_t)q * 8 * 72 + ((3 * 16 + m16) ^ swz);
    f16x8 B0, B1, B2, B3;
#pragma unroll
    for (int e = 0; e < 8; ++e) {
        B0[e] = Bb0[e * 72];
        B1[e] = Bb1[e * 72];
        B2[e] = Bb2[e * 72];
        B3[e] = Bb3[e * 72];
    }
    f16x8 ONES;
#pragma unroll
    for (int e = 0; e < 8; ++e) ONES[e] = (_Float16)1.f;
    f32x4 acc0 = {0.f,0.f,0.f,0.f}, acc1 = {0.f,0.f,0.f,0.f};
    f32x4 acc2 = {0.f,0.f,0.f,0.f}, acc3 = {0.f,0.f,0.f,0.f};
    f32x4 accD = {0.f,0.f,0.f,0.f};
    acc0 = __builtin_amdgcn_mfma_f32_16x16x32_f16(A, B0, acc0, 0, 0, 0);
    acc1 = __builtin_amdgcn_mfma_f32_16x16x32_f16(A, B1, acc1, 0, 0, 0);
    acc2 = __builtin_amdgcn_mfma_f32_16x16x32_f16(A, B2, acc2, 0, 0, 0);
    acc3 = __builtin_amdgcn_mfma_f32_16x16x32_f16(A, B3, acc3, 0, 0, 0);
    accD = __builtin_amdgcn_mfma_f32_16x16x32_f16(A, ONES, accD, 0, 0, 0);

    // combine hi + lo halves: lanes 0-15<->16-31 (A), 32-47<->48-63 (B)
    float tot[4][4], rdv[4];
#pragma unroll
    for (int r = 0; r < 4; ++r) {
        tot[0][r] = acc0[r] + __shfl_xor(acc0[r], 16);
        tot[1][r] = acc1[r] + __shfl_xor(acc1[r], 16);
        tot[2][r] = acc2[r] + __shfl_xor(acc2[r], 16);
        tot[3][r] = acc3[r] + __shfl_xor(acc3[r], 16);
        float d = accD[r] + __shfl_xor(accD[r], 16);
        rdv[r] = 1.f / (d + 1e-16f);
    }
    int outNode = -1;
    if (lane < 16) outNode = nodeA;
    else if (lane >= 32 && lane < 48 && nodeB != nodeA) outNode = nodeB;
    if (outNode >= 0) {
        size_t ob = (size_t)outNode * 256 + (lane & 15);
#pragma unroll
        for (int r = 0; r < 4; ++r) {
#pragma unroll
            for (int ct = 0; ct < 4; ++ct)
                aggout[ob + r * 64 + ct * 16] = (_Float16)(tot[ct][r] * rdv[r]);
        }
    }
}

// ---- GAT aggregate: long kernel (K=32 tiles, ones-MFMA denominators) ------

__global__ __launch_bounds__(256, 4) void gat_agg_long(
        const _Float16* __restrict__ h3,
        const float4* __restrict__ a_src4, const float4* __restrict__ a_dst4,
        const int* __restrict__ row_ptr, const int* __restrict__ col_src,
        const int* __restrict__ longList, const int* __restrict__ nodeCnts,
        _Float16* __restrict__ aggout) {
    __shared__ _Float16 HsAll[4][32 * 72];
    __shared__ _Float16 wATAll[4][16 * 40];
    int tid = threadIdx.x, lane = tid & 63, wid = tid >> 6;
    int nlong = nodeCnts[1];
    int li = blockIdx.x * 4 + wid;
    if (li >= nlong) return;
    int node = longList[li];
    _Float16* Hs = HsAll[wid];
    _Float16* wAT = wATAll[wid];

    int q = lane >> 4, m16 = lane & 15;
    float4 ad = a_dst4[node];
    int beg = row_ptr[node], end = row_ptr[node + 1];
    int deg = end - beg;
    int nslots = deg + 1;
    int c0 = (lane & 7) * 8;

    int swz = q << 4;
    const _Float16* Bb0 = Hs + (size_t)q * 8 * 72 + ((0 * 16 + m16) ^ swz);
    const _Float16* Bb1 = Hs + (size_t)q * 8 * 72 + ((1 * 16 + m16) ^ swz);
    const _Float16* Bb2 = Hs + (size_t)q * 8 * 72 + ((2 * 16 + m16) ^ swz);
    const _Float16* Bb3 = Hs + (size_t)q * 8 * 72 + ((3 * 16 + m16) ^ swz);
    const f16x8* Ab = (const f16x8*)(wAT + m16 * 40 + q * 8);
    f16x8 ONES;
#pragma unroll
    for (int e = 0; e < 8; ++e) ONES[e] = (_Float16)1.f;

    f32x4 acc0 = {0.f,0.f,0.f,0.f}, acc1 = {0.f,0.f,0.f,0.f};
    f32x4 acc2 = {0.f,0.f,0.f,0.f}, acc3 = {0.f,0.f,0.f,0.f};
    f32x4 accD = {0.f,0.f,0.f,0.f};
    float m0 = 0.f, m1 = 0.f, m2 = 0.f, m3 = 0.f;

    for (int base = 0; base < nslots; base += 32) {
        int sl = base + (lane & 31);
        int eidx = max(min(beg + sl - 1, end - 1), 0);
        int cs = (sl == 0) ? node : col_src[eidx];
        float4 as = a_src4[cs];
        float vm = (sl < nslots && lane < 32) ? 1.f : 0.f;
        float l0 = leaky02(as.x + ad.x);
        float l1 = leaky02(as.y + ad.y);
        float l2 = leaky02(as.z + ad.z);
        float l3 = leaky02(as.w + ad.w);
        if (base == 0) {
            m0 = red32max(vm > 0.f ? l0 : -1e30f);
            m1 = red32max(vm > 0.f ? l1 : -1e30f);
            m2 = red32max(vm > 0.f ? l2 : -1e30f);
            m3 = red32max(vm > 0.f ? l3 : -1e30f);
        }
        float w0 = vm * __expf(fminf(l0 - m0, 10.f));
        float w1 = vm * __expf(fminf(l1 - m1, 10.f));
        float w2 = vm * __expf(fminf(l2 - m2, 10.f));
        float w3 = vm * __expf(fminf(l3 - m3, 10.f));
        if (lane < 32) {
            int s32 = lane & 31;
            _Float16 h0 = (_Float16)w0, h1 = (_Float16)w1;
            _Float16 h2 = (_Float16)w2, h3v = (_Float16)w3;
            wAT[0 * 40 + s32] = h0;
            wAT[1 * 40 + s32] = h1;
            wAT[2 * 40 + s32] = h2;
            wAT[3 * 40 + s32] = h3v;
            wAT[4 * 40 + s32] = (_Float16)(w0 - (float)h0);
            wAT[5 * 40 + s32] = (_Float16)(w1 - (float)h1);
            wAT[6 * 40 + s32] = (_Float16)(w2 - (float)h2);
            wAT[7 * 40 + s32] = (_Float16)(w3 - (float)h3v);
        }
#pragma unroll
        for (int i = 0; i < 4; ++i) {
            int r = i * 8 + (lane >> 3);
            int s = __shfl(cs, r);
            half8 hv = *(const half8*)(h3 + (size_t)s * 64 + c0);
            *(half8*)(Hs + r * 72 + (c0 ^ (i << 4))) = hv;
        }
        __asm__ volatile("s_waitcnt lgkmcnt(0)" ::: "memory");
        f16x8 A = *Ab;
        f16x8 B0, B1, B2, B3;
#pragma unroll
        for (int e = 0; e < 8; ++e) {
            B0[e] = Bb0[e * 72];
            B1[e] = Bb1[e * 72];
            B2[e] = Bb2[e * 72];
            B3[e] = Bb3[e * 72];
        }
        acc0 = __builtin_amdgcn_mfma_f32_16x16x32_f16(A, B0, acc0, 0, 0, 0);
        acc1 = __builtin_amdgcn_mfma_f32_16x16x32_f16(A, B1, acc1, 0, 0, 0);
        acc2 = __builtin_amdgcn_mfma_f32_16x16x32_f16(A, B2, acc2, 0, 0, 0);
        acc3 = __builtin_amdgcn_mfma_f32_16x16x32_f16(A, B3, acc3, 0, 0, 0);
        accD = __builtin_amdgcn_mfma_f32_16x16x32_f16(A, ONES, accD, 0, 0, 0);
        __asm__ volatile("s_waitcnt lgkmcnt(0)" ::: "memory");
    }

    float tot[4][4], rdv[4];
#pragma unroll
    for (int r = 0; r < 4; ++r) {
        tot[0][r] = acc0[r] + __shfl_xor(acc0[r], 16);
        tot[1][r] = acc1[r] + __shfl_xor(acc1[r], 16);
        tot[2][r] = acc2[r] + __shfl_xor(acc2[r], 16);
        tot[3][r] = acc3[r] + __shfl_xor(acc3[r], 16);
        float d = accD[r] + __shfl_xor(accD[r], 16);
        rdv[r] = 1.f / (d + 1e-16f);
    }
    if (lane < 16) {
        size_t ob = (size_t)node * 256 + lane;
#pragma unroll
        for (int r = 0; r < 4; ++r) {
#pragma unroll
            for (int ct = 0; ct < 4; ++ct)
                aggout[ob + r * 64 + ct * 16] = (_Float16)(tot[ct][r] * rdv[r]);
        }
    }
}

// ---- MLP on matrix cores (unchanged) --------------------------------------

__global__ __launch_bounds__(256) void mlp_mfma(
        const _Float16* __restrict__ agg,
        const _Float16* __restrict__ CP,
        const float* __restrict__ bcomb,
        const float* __restrict__ wc2, const float* __restrict__ bc2,
        int n, float* __restrict__ out) {
    __shared__ float part[4][16][3];
    int tid = threadIdx.x;
    int lane = tid & 63;
    int w = __builtin_amdgcn_readfirstlane(tid >> 6);   // ct slice
    int c16 = lane & 15, hi = lane >> 4;

    f16x8 bh[8], blo[8];
#pragma unroll
    for (int kt = 0; kt < 8; ++kt) {
        bh[kt]  = *(const f16x8*)(CP + (size_t)(w * 8 + kt) * 512 + lane * 8);
        blo[kt] = *(const f16x8*)(CP + (size_t)(32 + w * 8 + kt) * 512 + lane * 8);
    }
    int col = w * 16 + c16;
    float bc  = bcomb[col];
    float w20 = wc2[col * 3 + 0], w21 = wc2[col * 3 + 1], w22 = wc2[col * 3 + 2];
    float bb0 = bc2[0], bb1 = bc2[1], bb2 = bc2[2];

    int ntiles = (n + 15) >> 4;
    for (int tile = blockIdx.x; tile < ntiles; tile += gridDim.x) {
        int rowb = tile * 16;
        int row = min(rowb + c16, n - 1);
        const _Float16* ap = agg + (size_t)row * 256 + hi * 8;
        f16x8 a[8];
#pragma unroll
        for (int kt = 0; kt < 8; ++kt) a[kt] = *(const f16x8*)(ap + kt * 32);
        f32x4 acc = {0.f, 0.f, 0.f, 0.f};
#pragma unroll
        for (int kt = 0; kt < 8; ++kt) {
            acc = __builtin_amdgcn_mfma_f32_16x16x32_f16(a[kt], bh[kt],  acc, 0, 0, 0);
            acc = __builtin_amdgcn_mfma_f32_16x16x32_f16(a[kt], blo[kt], acc, 0, 0, 0);
        }
        float pr[4][3];
#pragma unroll
        for (int r = 0; r < 4; ++r) {
            float z = fmaxf(acc[r] + bc, 0.f);
            pr[r][0] = red16(z * w20);
            pr[r][1] = red16(z * w21);
            pr[r][2] = red16(z * w22);
        }
        if (c16 == 0) {
#pragma unroll
            for (int r = 0; r < 4; ++r) {
                part[w][hi * 4 + r][0] = pr[r][0];
                part[w][hi * 4 + r][1] = pr[r][1];
                part[w][hi * 4 + r][2] = pr[r][2];
            }
        }
        __syncthreads();
        if (tid < 16) {
            int node = rowb + tid;
            if (node < n) {
                float e0 = part[0][tid][0] + part[1][tid][0] + part[2][tid][0] + part[3][tid][0] + bb0;
                float e1 = part[0][tid][1] + part[1][tid][1] + part[2][tid][1] + part[3][tid][1] + bb1;
                float e2 = part[0][tid][2] + part[1][tid][2] + part[2][tid][2] + part[3][tid][2] + bb2;
                float mx = fmaxf(e0, fmaxf(e1, e2));
                float lse = mx + logf(expf(e0 - mx) + expf(e1 - mx) + expf(e2 - mx));
                out[(size_t)node * 3 + 0] = e0 - lse;
                out[(size_t)node * 3 + 1] = e1 - lse;
                out[(size_t)node * 3 + 2] = e2 - lse;
            }
        }
        __syncthreads();
    }
}

// ---------------------------------------------------------------------------

extern "C" void kernel_launch(void* const* d_in, const int* in_sizes, int n_in,
                              void* d_out, int out_size, void* d_ws, size_t ws_size,
                              hipStream_t stream) {
    const float* x       = (const float*)d_in[0];
    const int*   ei      = (const int*)d_in[1];
    const float* w1      = (const float*)d_in[2];
    const float* b1      = (const float*)d_in[3];
    const float* w2      = (const float*)d_in[4];
    const float* b2      = (const float*)d_in[5];
    const float* w3      = (const float*)d_in[6];
    const float* b3      = (const float*)d_in[7];
    const float* wg      = (const float*)d_in[8];
    const float* bg      = (const float*)d_in[9];
    const float* att_s   = (const float*)d_in[10];
    const float* att_d   = (const float*)d_in[11];
    const float* wc1     = (const float*)d_in[12];
    const float* bc1     = (const float*)d_in[13];
    const float* wc2     = (const float*)d_in[14];
    const float* bc2     = (const float*)d_in[15];
    float* out = (float*)d_out;

    const int N = in_sizes[0] / 8;
    const int E = in_sizes[1] / 2;
    const int* srcv = ei;
    const int* dstv = ei + E;

    char* ws = (char*)d_ws;
    size_t off = 0;
    auto alloc = [&](size_t bytes) -> char* {
        char* p = ws + off;
        off += (bytes + 255) & ~(size_t)255;
        return p;
    };
    int*      counts    = (int*)alloc((size_t)N * 4);
    int*      row_ptr   = (int*)alloc((size_t)(N + 1) * 4);
    int*      cursor    = (int*)alloc((size_t)N * 4);
    int*      col_src   = (int*)alloc((size_t)E * 4);
    int*      blockSums = (int*)alloc(4096 * 4);
    int*      blockOffs = (int*)alloc(4096 * 4);
    float*    dinv      = (float*)alloc((size_t)N * 4);
    float*    rdinv     = (float*)alloc((size_t)N * 4);
    _Float16* xs        = (_Float16*)alloc((size_t)N * 8 * 2);
    float*    a_src     = (float*)alloc((size_t)N * 16);
    float*    a_dst     = (float*)alloc((size_t)N * 16);
    float*    wse       = (float*)alloc(256 * 4);
    float*    wde       = (float*)alloc(256 * 4);
    _Float16* CcombP    = (_Float16*)alloc(64 * 1024);           // fp16 hi+lo B-frags
    float*    bcomb     = (float*)alloc(64 * 4);
    _Float16* W2P       = (_Float16*)alloc(16 * 1024);           // gcn W frags
    _Float16* W3P       = (_Float16*)alloc(16 * 1024);
    int*      shortList = (int*)alloc((size_t)N * 4);
    int*      longList  = (int*)alloc((size_t)N * 4);
    int*      nodeCnts  = (int*)alloc(256);
    _Float16* bufA      = (_Float16*)alloc((size_t)N * 64 * 2);  // hs1, later h3
    _Float16* bufB      = (_Float16*)alloc((size_t)N * 64 * 2);  // hs2
    _Float16* aggbuf    = (_Float16*)alloc((size_t)N * 256 * 2); // 51.2MB fp16
    _Float16* hs1 = bufA;
    _Float16* hs2 = bufB;
    _Float16* h3  = bufA;   // hs1 dead once layer3 runs
    _Float16* aggA = aggbuf; // gcn agg rows alias aggbuf (dead until gat_agg)
    (void)ws_size; (void)n_in; (void)out_size;

    hipMemsetAsync(counts, 0, (size_t)N * 4, stream);
    hipMemsetAsync(nodeCnts, 0, 8, stream);

    const int TPB = 256;
    int range = (N + 7) / 8;
    count_kernel<<<1024, TPB, 0, stream>>>(dstv, E, range, counts);

    int NB = (N + 2047) / 2048;
    scan_pass1<<<NB, TPB, 0, stream>>>(counts, N, blockSums);
    scan_pass2<<<1, 64, 0, stream>>>(blockSums, NB, blockOffs);
    scan_pass3<<<NB, TPB, 0, stream>>>(counts, N, blockOffs, x,
                                       row_ptr, cursor, dinv, rdinv, xs,
                                       shortList, longList, nodeCnts);
    scatter_kernel<<<2048, TPB, 0, stream>>>(srcv, dstv, E, range, cursor, col_src);

    ccomb_kernel<<<385, 64, 0, stream>>>(wg, bg, wc1, bc1, att_s, att_d, w2, w3,
                                         CcombP, bcomb, wse, wde, W2P, W3P);

    int gridN = (N + 3) / 4;
    gcn_layer1<<<gridN, TPB, 0, stream>>>((const half8*)xs, w1, b1, row_ptr, col_src,
                                          dinv, N, hs1);

    gcn_agg<<<gridN, TPB, 0, stream>>>(hs1, row_ptr, col_src, dinv, N, aggA);
    gcn_mfma<false><<<2048, TPB, 0, stream>>>(aggA, W2P, b2, hs1, dinv, rdinv,
                                              nullptr, nullptr, N, hs2,
                                              nullptr, nullptr);
    gcn_agg<<<gridN, TPB, 0, stream>>>(hs2, row_ptr, col_src, dinv, N, aggA);
    gcn_mfma<true><<<2048, TPB, 0, stream>>>(aggA, W3P, b3, hs2, dinv, rdinv,
                                             wse, wde, N, h3,
                                             (float4*)a_src, (float4*)a_dst);

    int gridS = ((N + 1) / 2 + 3) / 4;   // worst case all-short
    gat_agg_short<<<gridS, TPB, 0, stream>>>(h3, (const float4*)a_src,
                                             (const float4*)a_dst, row_ptr, col_src,
                                             shortList, nodeCnts, aggbuf);
    gat_agg_long<<<gridN, TPB, 0, stream>>>(h3, (const float4*)a_src,
                                            (const float4*)a_dst, row_ptr, col_src,
                                            longList, nodeCnts, aggbuf);
    mlp_mfma<<<2048, TPB, 0, stream>>>(aggbuf, CcombP, bcomb, wc2, bc2, N, out);
}

// Round 10
// 512.509 us; speedup vs baseline: 2.5067x; 2.5067x over previous
//
#include <hip/hip_runtime.h>
#include <math.h>

// ---------------------------------------------------------------------------
// SpatialGNN: 3x GCN (residual) + 4-head GAT + MLP + log_softmax
// N=100000, E=1600000, IN=8, HID=64, HEADS=4, OUT=3
//
// R20 = R19 with the scan_pass3 atomic hotspot fixed (R19: 776us there —
// 100K atomicAdds to 2 global addresses, cross-XCD cacheline bounce).
//  - partition now uses a block-local packed prefix scan (short|long<<16)
//    + ONE atomicAdd per list per block (98 total), then scatters entries
//    at base + exclusive prefix. Guideline 12 compliance.
//  - gat_agg_short / gat_agg_long / everything else: identical to R19
//    (which passed verification; only the list build was pathological).
// ---------------------------------------------------------------------------

typedef _Float16 half8 __attribute__((ext_vector_type(8)));
typedef _Float16 f16x8 __attribute__((ext_vector_type(8)));
typedef float f32x4 __attribute__((ext_vector_type(4)));

__device__ __forceinline__ float leaky02(float v) { return v > 0.f ? v : 0.2f * v; }

// ---- cross-lane reduction helpers (DPP/swizzle; minimize DS-pipe ops) -----

template <int CTRL>
__device__ __forceinline__ float dpp_add(float v) {
    int iv = __builtin_bit_cast(int, v);
    int r = __builtin_amdgcn_update_dpp(iv, iv, CTRL, 0xF, 0xF, false);
    return v + __builtin_bit_cast(float, r);
}
template <int OFF>
__device__ __forceinline__ float swz_add(float v) {
    int r = __builtin_amdgcn_ds_swizzle(__builtin_bit_cast(int, v), OFF);
    return v + __builtin_bit_cast(float, r);
}
template <int CTRL>
__device__ __forceinline__ float dpp_max(float v) {
    int iv = __builtin_bit_cast(int, v);
    int r = __builtin_amdgcn_update_dpp(iv, iv, CTRL, 0xF, 0xF, false);
    return fmaxf(v, __builtin_bit_cast(float, r));
}
template <int OFF>
__device__ __forceinline__ float swz_max(float v) {
    int r = __builtin_amdgcn_ds_swizzle(__builtin_bit_cast(int, v), OFF);
    return fmaxf(v, __builtin_bit_cast(float, r));
}
__device__ __forceinline__ float red8(float v) {
    v = dpp_add<0xB1>(v);     // xor1
    v = dpp_add<0x4E>(v);     // xor2
    v = swz_add<0x101F>(v);   // xor4
    return v;
}
__device__ __forceinline__ float red16(float v) {
    v = dpp_add<0xB1>(v);
    v = dpp_add<0x4E>(v);
    v = swz_add<0x101F>(v);
    v = dpp_add<0x128>(v);    // row_ror:8 -> completes 16-lane sum
    return v;
}
__device__ __forceinline__ float red16max(float v) {   // max within 16-lane group
    v = dpp_max<0xB1>(v);
    v = dpp_max<0x4E>(v);
    v = swz_max<0x101F>(v);
    v = dpp_max<0x128>(v);
    return v;
}
__device__ __forceinline__ float red64(float v) {
    v = dpp_add<0xB1>(v);
    v = dpp_add<0x4E>(v);
    v = swz_add<0x101F>(v);
    v = dpp_add<0x128>(v);    // xor8: row_ror:8
    v = swz_add<0x401F>(v);   // xor16
    v = v + __shfl_xor(v, 32);
    return v;
}
__device__ __forceinline__ float red32max(float v) {   // max within each 32-lane half
    v = dpp_max<0xB1>(v);
    v = dpp_max<0x4E>(v);
    v = swz_max<0x101F>(v);
    v = dpp_max<0x128>(v);
    v = swz_max<0x401F>(v);
    return v;
}

// ---- CSR build ------------------------------------------------------------

// XCD-range-filtered count: group blockIdx&7 counts only its dst range.
__global__ void count_kernel(const int* __restrict__ dst, int E, int range,
                             int* __restrict__ counts) {
    int grp = blockIdx.x & 7;
    int nlo = grp * range;
    int nhi = nlo + range;
    int nblk = gridDim.x >> 3;
    int c = blockIdx.x >> 3;
    int stride = nblk * blockDim.x;
    for (int e = c * blockDim.x + threadIdx.x; e < E; e += stride) {
        int d = dst[e];
        if (d >= nlo && d < nhi) atomicAdd(&counts[d], 1);
    }
}

__global__ void scan_pass1(const int* __restrict__ counts, int n, int* __restrict__ blockSums) {
    __shared__ int sh[256];
    int base = blockIdx.x * 2048;
    int tid = threadIdx.x;
    int s = 0;
#pragma unroll
    for (int j = 0; j < 8; ++j) {
        int idx = base + tid * 8 + j;
        if (idx < n) s += counts[idx];
    }
    sh[tid] = s;
    __syncthreads();
    for (int off = 128; off > 0; off >>= 1) {
        if (tid < off) sh[tid] += sh[tid + off];
        __syncthreads();
    }
    if (tid == 0) blockSums[blockIdx.x] = sh[0];
}

__global__ void scan_pass2(const int* __restrict__ blockSums, int nb, int* __restrict__ blockOffs) {
    if (threadIdx.x == 0 && blockIdx.x == 0) {
        int run = 0;
        for (int i = 0; i < nb; ++i) { blockOffs[i] = run; run += blockSums[i]; }
    }
}

__global__ void scan_pass3(const int* __restrict__ counts, int n,
                           const int* __restrict__ blockOffs,
                           const float* __restrict__ x,
                           int* __restrict__ row_ptr, int* __restrict__ cursor,
                           float* __restrict__ dinv, float* __restrict__ rdinv,
                           _Float16* __restrict__ xs,
                           int* __restrict__ shortList, int* __restrict__ longList,
                           int* __restrict__ nodeCnts) {
    __shared__ int sh[256];
    __shared__ int shp[256];
    __shared__ int baseS, baseL;
    int base = blockIdx.x * 2048;
    int tid = threadIdx.x;
    int cnt[8];
    int local = 0;
#pragma unroll
    for (int j = 0; j < 8; ++j) {
        int idx = base + tid * 8 + j;
        cnt[j] = (idx < n) ? counts[idx] : 0;
        local += cnt[j];
    }
    sh[tid] = local;
    __syncthreads();
    for (int off = 1; off < 256; off <<= 1) {
        int v = (tid >= off) ? sh[tid - off] : 0;
        __syncthreads();
        sh[tid] += v;
        __syncthreads();
    }
    int run = blockOffs[blockIdx.x] + sh[tid] - local;
#pragma unroll
    for (int j = 0; j < 8; ++j) {
        int idx = base + tid * 8 + j;
        if (idx < n) {
            row_ptr[idx] = run;
            cursor[idx] = run;
            float dv = rsqrtf((float)(cnt[j] + 1));
            dinv[idx] = dv;
            rdinv[idx] = sqrtf((float)(cnt[j] + 1));
#pragma unroll
            for (int t = 0; t < 8; ++t) xs[idx * 8 + t] = (_Float16)(dv * x[idx * 8 + t]);
            run += cnt[j];
            if (idx == n - 1) row_ptr[n] = run;
        }
    }
    // ---- degree partition, block-local scan + 1 atomic per list per block --
    int myS = 0, myL = 0;
#pragma unroll
    for (int j = 0; j < 8; ++j) {
        int idx = base + tid * 8 + j;
        if (idx < n) { if (cnt[j] <= 15) ++myS; else ++myL; }
    }
    shp[tid] = myS | (myL << 16);   // per-block totals <= 2048, no overflow
    __syncthreads();
    for (int off = 1; off < 256; off <<= 1) {
        int v = (tid >= off) ? shp[tid - off] : 0;
        __syncthreads();
        shp[tid] += v;
        __syncthreads();
    }
    if (tid == 255) {
        baseS = atomicAdd(&nodeCnts[0], shp[255] & 0xFFFF);
        baseL = atomicAdd(&nodeCnts[1], shp[255] >> 16);
    }
    __syncthreads();
    int pS = baseS + (shp[tid] & 0xFFFF) - myS;
    int pL = baseL + (shp[tid] >> 16) - myL;
#pragma unroll
    for (int j = 0; j < 8; ++j) {
        int idx = base + tid * 8 + j;
        if (idx < n) {
            if (cnt[j] <= 15) shortList[pS++] = idx;
            else              longList[pL++] = idx;
        }
    }
}

// XCD-range-filtered scatter (R9, kept): col_src/cursor writes stay XCD-local.
__global__ void scatter_kernel(const int* __restrict__ src, const int* __restrict__ dst,
                               int E, int range,
                               int* __restrict__ cursor, int* __restrict__ col_src) {
    int grp = blockIdx.x & 7;
    int nlo = grp * range;
    int nhi = nlo + range;
    int nblk = gridDim.x >> 3;
    int c = blockIdx.x >> 3;
    int stride = nblk * blockDim.x;
    for (int e = c * blockDim.x + threadIdx.x; e < E; e += stride) {
        int d = dst[e];
        if (d >= nlo && d < nhi) {
            int pos = atomicAdd(&cursor[d], 1);
            col_src[pos] = src[e];
        }
    }
}

// ---- weight precompute: Ccomb + W2P/W3P (fp16 split, B-frag order) --------
// B-frag packing (validated by mlp_mfma): for k index i, out-ch j:
//   kt = i>>5, l = (((i>>3)&3)<<4)|(j&15), e = i&7, ct = j>>4.

__global__ void ccomb_kernel(const float* __restrict__ Wg, const float* __restrict__ bg,
                             const float* __restrict__ wc1, const float* __restrict__ bc1,
                             const float* __restrict__ att_src, const float* __restrict__ att_dst,
                             const float* __restrict__ w2, const float* __restrict__ w3,
                             _Float16* __restrict__ CcombP, float* __restrict__ bcomb,
                             float* __restrict__ wse, float* __restrict__ wde,
                             _Float16* __restrict__ W2P, _Float16* __restrict__ W3P) {
    int bid = blockIdx.x;   // 0..384
    int j = threadIdx.x;    // 64 threads
    if (bid < 256) {
        int i = bid;        // k index (agg channel)
        float s = 0.f;
        for (int c = 0; c < 64; ++c)
            s += Wg[(i & 63) * 256 + (i >> 6) * 64 + c] * wc1[((i >> 6) * 64 + c) * 64 + j];
        _Float16 hi = (_Float16)s;
        _Float16 lo = (_Float16)(s - (float)hi);
        int kt = i >> 5, l = (((i >> 3) & 3) << 4) | (j & 15), e = i & 7, ct = j >> 4;
        CcombP[(ct * 8 + kt) * 512 + l * 8 + e] = hi;
        CcombP[(32 + ct * 8 + kt) * 512 + l * 8 + e] = lo;
    } else if (bid == 256) {
        float s = bc1[j];
        for (int i = 0; i < 256; ++i) s += bg[i] * wc1[i * 64 + j];
        bcomb[j] = s;
#pragma unroll
        for (int h = 0; h < 4; ++h) {
            float ss = 0.f, sd = 0.f;
            for (int c = 0; c < 64; ++c) {
                float w = Wg[j * 256 + h * 64 + c];
                ss += w * att_src[h * 64 + c];
                sd += w * att_dst[h * 64 + c];
            }
            wse[j * 4 + h] = ss;
            wde[j * 4 + h] = sd;
        }
    } else {
        // W2P / W3P: K=64, 8 frags (ct*2+kt) hi + 8 lo
        int i = (bid < 321) ? (bid - 257) : (bid - 321);
        const float* W = (bid < 321) ? w2 : w3;
        _Float16* WP = (bid < 321) ? W2P : W3P;
        float s = W[i * 64 + j];
        _Float16 hi = (_Float16)s;
        _Float16 lo = (_Float16)(s - (float)hi);
        int kt = i >> 5, l = (((i >> 3) & 3) << 4) | (j & 15), e = i & 7, ct = j >> 4;
        WP[(ct * 2 + kt) * 512 + l * 8 + e] = hi;
        WP[(8 + ct * 2 + kt) * 512 + l * 8 + e] = lo;
    }
}

// ---- GCN layer 1: one edge per lane (16B half8 row) -----------------------

__global__ void gcn_layer1(const half8* __restrict__ xs8,
                           const float* __restrict__ W1, const float* __restrict__ b1,
                           const int* __restrict__ row_ptr, const int* __restrict__ col_src,
                           const float* __restrict__ dinv, int n,
                           _Float16* __restrict__ hs1) {
    int tid = threadIdx.x, lane = tid & 63, wid = tid >> 6;
    int node = blockIdx.x * 4 + wid;
    if (node >= n) return;
    int beg = row_ptr[node], end = row_ptr[node + 1];
    int deg = end - beg;
    float acc[8] = {0.f, 0.f, 0.f, 0.f, 0.f, 0.f, 0.f, 0.f};
    for (int base = 0; base < deg; base += 64) {
        int cs = col_src[min(beg + base + lane, end - 1)];
        half8 v = xs8[cs];
        if (base + lane < deg) {
#pragma unroll
            for (int c = 0; c < 8; ++c) acc[c] += (float)v[c];
        }
    }
#pragma unroll
    for (int c = 0; c < 8; ++c) acc[c] = red64(acc[c]);
    half8 sv = xs8[node];
    float di = dinv[node];
    float agg[8];
#pragma unroll
    for (int c = 0; c < 8; ++c) agg[c] = (acc[c] + (float)sv[c]) * di;
    float sum = b1[lane];
#pragma unroll
    for (int k = 0; k < 8; ++k) sum = fmaf(agg[k], W1[k * 64 + lane], sum);
    hs1[node * 64 + lane] = (_Float16)(di * fmaxf(sum, 0.f));
}

// ---- GCN aggregation: gather + red8 + dinv -> fp16 agg rows ---------------

__global__ void gcn_agg(const _Float16* __restrict__ hs_in,
                        const int* __restrict__ row_ptr, const int* __restrict__ col_src,
                        const float* __restrict__ dinv, int n,
                        _Float16* __restrict__ aggout) {
    int tid = threadIdx.x, lane = tid & 63, wid = tid >> 6;
    int node = blockIdx.x * 4 + wid;
    if (node >= n) return;
    int t = lane >> 3, g = lane & 7;
    const half8* hs8 = (const half8*)hs_in;
    int beg = row_ptr[node], end = row_ptr[node + 1];
    int deg = end - beg;
    half8 sv = hs8[node * 8 + t];
    float ac[8];
#pragma unroll
    for (int c = 0; c < 8; ++c) ac[c] = (g == 0) ? (float)sv[c] : 0.f;
    for (int base = 0; base < deg; base += 64) {
        int cs = col_src[min(beg + base + lane, end - 1)];
        int lim = min(deg - base, 64);
        auto bodyF = [&](int eo8) {
            int s = __shfl(cs, eo8 + g);
            half8 v = hs8[s * 8 + t];
#pragma unroll
            for (int c = 0; c < 8; ++c) ac[c] += (float)v[c];
        };
        auto bodyG = [&](int eo8) {
            int eo = eo8 + g;
            int s = __shfl(cs, eo);
            half8 v = hs8[s * 8 + t];
            if (eo < lim) {
#pragma unroll
                for (int c = 0; c < 8; ++c) ac[c] += (float)v[c];
            }
        };
        int eo8 = 0;
        for (; eo8 + 16 <= lim; eo8 += 16) { bodyF(eo8); bodyF(eo8 + 8); }
        if (eo8 < lim) {
            bodyG(eo8);
            eo8 += 8;
            if (eo8 < lim) bodyG(eo8);
        }
    }
    float di = dinv[node];
#pragma unroll
    for (int c = 0; c < 8; ++c) ac[c] = red8(ac[c]) * di;
    if (g == 0) {
        half8 hv;
#pragma unroll
        for (int c = 0; c < 8; ++c) hv[c] = (_Float16)ac[c];
        *(half8*)(aggout + (size_t)node * 64 + t * 8) = hv;
    }
}

// ---- GCN transform on matrix cores: Z = relu(agg @ W + b), residual -------

template <bool LAST>
__global__ __launch_bounds__(256) void gcn_mfma(
        const _Float16* __restrict__ agg,
        const _Float16* __restrict__ WP,
        const float* __restrict__ b,
        const _Float16* __restrict__ hs_in,
        const float* __restrict__ dinv, const float* __restrict__ rdinv,
        const float* __restrict__ wse, const float* __restrict__ wde,
        int n, _Float16* __restrict__ hout,
        float4* __restrict__ a_src4, float4* __restrict__ a_dst4) {
    __shared__ float partS[4][16][4];
    __shared__ float partD[4][16][4];
    int tid = threadIdx.x;
    int lane = tid & 63;
    int w = __builtin_amdgcn_readfirstlane(tid >> 6);   // ct slice
    int c16 = lane & 15, hi = lane >> 4;

    f16x8 bh[2], blo[2];
#pragma unroll
    for (int kt = 0; kt < 2; ++kt) {
        bh[kt]  = *(const f16x8*)(WP + (size_t)(w * 2 + kt) * 512 + lane * 8);
        blo[kt] = *(const f16x8*)(WP + (size_t)(8 + w * 2 + kt) * 512 + lane * 8);
    }
    int col = w * 16 + c16;
    float bl = b[col];
    float4 wev, wdv;
    if (LAST) {
        wev = ((const float4*)wse)[col];
        wdv = ((const float4*)wde)[col];
    }

    int ntiles = (n + 15) >> 4;
    for (int tile = blockIdx.x; tile < ntiles; tile += gridDim.x) {
        int rowb = tile * 16;
        int arow = min(rowb + c16, n - 1);
        const _Float16* ap = agg + (size_t)arow * 64 + hi * 8;
        f16x8 a0 = *(const f16x8*)(ap);
        f16x8 a1 = *(const f16x8*)(ap + 32);
        f32x4 acc = {0.f, 0.f, 0.f, 0.f};
        acc = __builtin_amdgcn_mfma_f32_16x16x32_f16(a0, bh[0],  acc, 0, 0, 0);
        acc = __builtin_amdgcn_mfma_f32_16x16x32_f16(a0, blo[0], acc, 0, 0, 0);
        acc = __builtin_amdgcn_mfma_f32_16x16x32_f16(a1, bh[1],  acc, 0, 0, 0);
        acc = __builtin_amdgcn_mfma_f32_16x16x32_f16(a1, blo[1], acc, 0, 0, 0);
#pragma unroll
        for (int r = 0; r < 4; ++r) {
            int noder = rowb + hi * 4 + r;
            bool ok = noder < n;
            int ni = min(noder, n - 1);
            float hp = rdinv[ni] * (float)hs_in[(size_t)ni * 64 + col];
            float z = fmaxf(acc[r] + bl, 0.f);
            float hv = hp + z;
            if (!LAST) {
                if (ok) hout[(size_t)ni * 64 + col] = (_Float16)(dinv[ni] * hv);
            } else {
                if (ok) hout[(size_t)ni * 64 + col] = (_Float16)hv;
                float s0 = red16(hv * wev.x), s1 = red16(hv * wev.y);
                float s2 = red16(hv * wev.z), s3 = red16(hv * wev.w);
                float d0 = red16(hv * wdv.x), d1 = red16(hv * wdv.y);
                float d2 = red16(hv * wdv.z), d3 = red16(hv * wdv.w);
                if (c16 == 0) {
                    *(float4*)&partS[w][hi * 4 + r][0] = make_float4(s0, s1, s2, s3);
                    *(float4*)&partD[w][hi * 4 + r][0] = make_float4(d0, d1, d2, d3);
                }
            }
        }
        if (LAST) {
            __syncthreads();
            if (tid < 16) {
                int node = rowb + tid;
                if (node < n) {
                    float4 s = make_float4(
                        partS[0][tid][0] + partS[1][tid][0] + partS[2][tid][0] + partS[3][tid][0],
                        partS[0][tid][1] + partS[1][tid][1] + partS[2][tid][1] + partS[3][tid][1],
                        partS[0][tid][2] + partS[1][tid][2] + partS[2][tid][2] + partS[3][tid][2],
                        partS[0][tid][3] + partS[1][tid][3] + partS[2][tid][3] + partS[3][tid][3]);
                    float4 d = make_float4(
                        partD[0][tid][0] + partD[1][tid][0] + partD[2][tid][0] + partD[3][tid][0],
                        partD[0][tid][1] + partD[1][tid][1] + partD[2][tid][1] + partD[3][tid][1],
                        partD[0][tid][2] + partD[1][tid][2] + partD[2][tid][2] + partD[3][tid][2],
                        partD[0][tid][3] + partD[1][tid][3] + partD[2][tid][3] + partD[3][tid][3]);
                    a_src4[node] = s;
                    a_dst4[node] = d;
                }
            }
            __syncthreads();
        }
    }
}

// ---- GAT aggregate: short kernel (2 nodes per wave, one K=32 MFMA tile) ---

__global__ __launch_bounds__(256, 4) void gat_agg_short(
        const _Float16* __restrict__ h3,
        const float4* __restrict__ a_src4, const float4* __restrict__ a_dst4,
        const int* __restrict__ row_ptr, const int* __restrict__ col_src,
        const int* __restrict__ shortList, const int* __restrict__ nodeCnts,
        _Float16* __restrict__ aggout) {
    __shared__ _Float16 HsAll[4][32 * 72];
    __shared__ _Float16 wATAll[4][16 * 40];
    int tid = threadIdx.x, lane = tid & 63, wid = tid >> 6;
    int nshort = nodeCnts[0];
    int i0 = (blockIdx.x * 4 + wid) * 2;
    if (i0 >= nshort) return;
    int nodeA = shortList[i0];
    int nodeB = (i0 + 1 < nshort) ? shortList[i0 + 1] : nodeA;
    _Float16* Hs = HsAll[wid];
    _Float16* wAT = wATAll[wid];

    // zero dead quadrants: rows 0-7 cols 16-31, rows 8-15 cols 0-15
    {
        int zm = lane >> 2;
        int zc = ((zm < 8) ? 16 : 0) + (lane & 3) * 4;
#pragma unroll
        for (int j = 0; j < 4; ++j) wAT[zm * 40 + zc + j] = (_Float16)0.f;
    }

    int q = lane >> 4, m16 = lane & 15;
    int c0 = (lane & 7) * 8;
    int sl16 = lane & 15;
    int myNode = (lane < 16) ? nodeA : ((lane < 32) ? nodeB : nodeA);
    int begL = row_ptr[myNode], endL = row_ptr[myNode + 1];
    int nslL = endL - begL + 1;
    float4 adv = a_dst4[myNode];
    int eidx = max(min(begL + sl16 - 1, endL - 1), 0);
    int cs = (sl16 == 0) ? myNode : col_src[eidx];
    float4 as = a_src4[cs];
    float vm = (sl16 < nslL && lane < 32) ? 1.f : 0.f;
    float l0 = leaky02(as.x + adv.x);
    float l1 = leaky02(as.y + adv.y);
    float l2 = leaky02(as.z + adv.z);
    float l3 = leaky02(as.w + adv.w);
    float m0 = red16max(vm > 0.f ? l0 : -1e30f);
    float m1 = red16max(vm > 0.f ? l1 : -1e30f);
    float m2 = red16max(vm > 0.f ? l2 : -1e30f);
    float m3 = red16max(vm > 0.f ? l3 : -1e30f);
    float w0 = vm * __expf(fminf(l0 - m0, 10.f));
    float w1 = vm * __expf(fminf(l1 - m1, 10.f));
    float w2 = vm * __expf(fminf(l2 - m2, 10.f));
    float w3 = vm * __expf(fminf(l3 - m3, 10.f));
    if (lane < 32) {
        int rb = (lane < 16) ? 0 : 8;          // node A rows 0-7, B rows 8-15
        int k = lane;                          // A: k 0-15, B: k 16-31
        _Float16 h0 = (_Float16)w0, h1 = (_Float16)w1;
        _Float16 h2 = (_Float16)w2, h3v = (_Float16)w3;
        wAT[(rb + 0) * 40 + k] = h0;
        wAT[(rb + 1) * 40 + k] = h1;
        wAT[(rb + 2) * 40 + k] = h2;
        wAT[(rb + 3) * 40 + k] = h3v;
        wAT[(rb + 4) * 40 + k] = (_Float16)(w0 - (float)h0);
        wAT[(rb + 5) * 40 + k] = (_Float16)(w1 - (float)h1);
        wAT[(rb + 6) * 40 + k] = (_Float16)(w2 - (float)h2);
        wAT[(rb + 7) * 40 + k] = (_Float16)(w3 - (float)h3v);
    }
    // H gather: rows 0-15 node A sources, 16-31 node B (cs lanes 0-31)
#pragma unroll
    for (int i = 0; i < 4; ++i) {
        int r = i * 8 + (lane >> 3);
        int s = __shfl(cs, r);
        half8 hv = *(const half8*)(h3 + (size_t)s * 64 + c0);
        *(half8*)(Hs + r * 72 + (c0 ^ (i << 4))) = hv;
    }
    __asm__ volatile("s_waitcnt lgkmcnt(0)" ::: "memory");
    f16x8 A = *(const f16x8*)(wAT + m16 * 40 + q * 8);
    int swz = q << 4;
    const _Float16* Bb0 = Hs + (size_t)q * 8 * 72 + ((0 * 16 + m16) ^ swz);
    const _Float16* Bb1 = Hs + (size_t)q * 8 * 72 + ((1 * 16 + m16) ^ swz);
    const _Float16* Bb2 = Hs + (size_t)q * 8 * 72 + ((2 * 16 + m16) ^ swz);
    const _Float16* Bb3 = Hs + (size_t)q * 8 * 72 + ((3 * 16 + m16) ^ swz);
    f16x8 B0, B1, B2, B3;
#pragma unroll
    for (int e = 0; e < 8; ++e) {
        B0[e] = Bb0[e * 72];
        B1[e] = Bb1[e * 72];
        B2[e] = Bb2[e * 72];
        B3[e] = Bb3[e * 72];
    }
    f16x8 ONES;
#pragma unroll
    for (int e = 0; e < 8; ++e) ONES[e] = (_Float16)1.f;
    f32x4 acc0 = {0.f,0.f,0.f,0.f}, acc1 = {0.f,0.f,0.f,0.f};
    f32x4 acc2 = {0.f,0.f,0.f,0.f}, acc3 = {0.f,0.f,0.f,0.f};
    f32x4 accD = {0.f,0.f,0.f,0.f};
    acc0 = __builtin_amdgcn_mfma_f32_16x16x32_f16(A, B0, acc0, 0, 0, 0);
    acc1 = __builtin_amdgcn_mfma_f32_16x16x32_f16(A, B1, acc1, 0, 0, 0);
    acc2 = __builtin_amdgcn_mfma_f32_16x16x32_f16(A, B2, acc2, 0, 0, 0);
    acc3 = __builtin_amdgcn_mfma_f32_16x16x32_f16(A, B3, acc3, 0, 0, 0);
    accD = __builtin_amdgcn_mfma_f32_16x16x32_f16(A, ONES, accD, 0, 0, 0);

    // combine hi + lo halves: lanes 0-15<->16-31 (A), 32-47<->48-63 (B)
    float tot[4][4], rdv[4];
#pragma unroll
    for (int r = 0; r < 4; ++r) {
        tot[0][r] = acc0[r] + __shfl_xor(acc0[r], 16);
        tot[1][r] = acc1[r] + __shfl_xor(acc1[r], 16);
        tot[2][r] = acc2[r] + __shfl_xor(acc2[r], 16);
        tot[3][r] = acc3[r] + __shfl_xor(acc3[r], 16);
        float d = accD[r] + __shfl_xor(accD[r], 16);
        rdv[r] = 1.f / (d + 1e-16f);
    }
    int outNode = -1;
    if (lane < 16) outNode = nodeA;
    else if (lane >= 32 && lane < 48 && nodeB != nodeA) outNode = nodeB;
    if (outNode >= 0) {
        size_t ob = (size_t)outNode * 256 + (lane & 15);
#pragma unroll
        for (int r = 0; r < 4; ++r) {
#pragma unroll
            for (int ct = 0; ct < 4; ++ct)
                aggout[ob + r * 64 + ct * 16] = (_Float16)(tot[ct][r] * rdv[r]);
        }
    }
}

// ---- GAT aggregate: long kernel (K=32 tiles, ones-MFMA denominators) ------

__global__ __launch_bounds__(256, 4) void gat_agg_long(
        const _Float16* __restrict__ h3,
        const float4* __restrict__ a_src4, const float4* __restrict__ a_dst4,
        const int* __restrict__ row_ptr, const int* __restrict__ col_src,
        const int* __restrict__ longList, const int* __restrict__ nodeCnts,
        _Float16* __restrict__ aggout) {
    __shared__ _Float16 HsAll[4][32 * 72];
    __shared__ _Float16 wATAll[4][16 * 40];
    int tid = threadIdx.x, lane = tid & 63, wid = tid >> 6;
    int nlong = nodeCnts[1];
    int li = blockIdx.x * 4 + wid;
    if (li >= nlong) return;
    int node = longList[li];
    _Float16* Hs = HsAll[wid];
    _Float16* wAT = wATAll[wid];

    int q = lane >> 4, m16 = lane & 15;
    float4 ad = a_dst4[node];
    int beg = row_ptr[node], end = row_ptr[node + 1];
    int deg = end - beg;
    int nslots = deg + 1;
    int c0 = (lane & 7) * 8;

    int swz = q << 4;
    const _Float16* Bb0 = Hs + (size_t)q * 8 * 72 + ((0 * 16 + m16) ^ swz);
    const _Float16* Bb1 = Hs + (size_t)q * 8 * 72 + ((1 * 16 + m16) ^ swz);
    const _Float16* Bb2 = Hs + (size_t)q * 8 * 72 + ((2 * 16 + m16) ^ swz);
    const _Float16* Bb3 = Hs + (size_t)q * 8 * 72 + ((3 * 16 + m16) ^ swz);
    const f16x8* Ab = (const f16x8*)(wAT + m16 * 40 + q * 8);
    f16x8 ONES;
#pragma unroll
    for (int e = 0; e < 8; ++e) ONES[e] = (_Float16)1.f;

    f32x4 acc0 = {0.f,0.f,0.f,0.f}, acc1 = {0.f,0.f,0.f,0.f};
    f32x4 acc2 = {0.f,0.f,0.f,0.f}, acc3 = {0.f,0.f,0.f,0.f};
    f32x4 accD = {0.f,0.f,0.f,0.f};
    float m0 = 0.f, m1 = 0.f, m2 = 0.f, m3 = 0.f;

    for (int base = 0; base < nslots; base += 32) {
        int sl = base + (lane & 31);
        int eidx = max(min(beg + sl - 1, end - 1), 0);
        int cs = (sl == 0) ? node : col_src[eidx];
        float4 as = a_src4[cs];
        float vm = (sl < nslots && lane < 32) ? 1.f : 0.f;
        float l0 = leaky02(as.x + ad.x);
        float l1 = leaky02(as.y + ad.y);
        float l2 = leaky02(as.z + ad.z);
        float l3 = leaky02(as.w + ad.w);
        if (base == 0) {
            m0 = red32max(vm > 0.f ? l0 : -1e30f);
            m1 = red32max(vm > 0.f ? l1 : -1e30f);
            m2 = red32max(vm > 0.f ? l2 : -1e30f);
            m3 = red32max(vm > 0.f ? l3 : -1e30f);
        }
        float w0 = vm * __expf(fminf(l0 - m0, 10.f));
        float w1 = vm * __expf(fminf(l1 - m1, 10.f));
        float w2 = vm * __expf(fminf(l2 - m2, 10.f));
        float w3 = vm * __expf(fminf(l3 - m3, 10.f));
        if (lane < 32) {
            int s32 = lane & 31;
            _Float16 h0 = (_Float16)w0, h1 = (_Float16)w1;
            _Float16 h2 = (_Float16)w2, h3v = (_Float16)w3;
            wAT[0 * 40 + s32] = h0;
            wAT[1 * 40 + s32] = h1;
            wAT[2 * 40 + s32] = h2;
            wAT[3 * 40 + s32] = h3v;
            wAT[4 * 40 + s32] = (_Float16)(w0 - (float)h0);
            wAT[5 * 40 + s32] = (_Float16)(w1 - (float)h1);
            wAT[6 * 40 + s32] = (_Float16)(w2 - (float)h2);
            wAT[7 * 40 + s32] = (_Float16)(w3 - (float)h3v);
        }
#pragma unroll
        for (int i = 0; i < 4; ++i) {
            int r = i * 8 + (lane >> 3);
            int s = __shfl(cs, r);
            half8 hv = *(const half8*)(h3 + (size_t)s * 64 + c0);
            *(half8*)(Hs + r * 72 + (c0 ^ (i << 4))) = hv;
        }
        __asm__ volatile("s_waitcnt lgkmcnt(0)" ::: "memory");
        f16x8 A = *Ab;
        f16x8 B0, B1, B2, B3;
#pragma unroll
        for (int e = 0; e < 8; ++e) {
            B0[e] = Bb0[e * 72];
            B1[e] = Bb1[e * 72];
            B2[e] = Bb2[e * 72];
            B3[e] = Bb3[e * 72];
        }
        acc0 = __builtin_amdgcn_mfma_f32_16x16x32_f16(A, B0, acc0, 0, 0, 0);
        acc1 = __builtin_amdgcn_mfma_f32_16x16x32_f16(A, B1, acc1, 0, 0, 0);
        acc2 = __builtin_amdgcn_mfma_f32_16x16x32_f16(A, B2, acc2, 0, 0, 0);
        acc3 = __builtin_amdgcn_mfma_f32_16x16x32_f16(A, B3, acc3, 0, 0, 0);
        accD = __builtin_amdgcn_mfma_f32_16x16x32_f16(A, ONES, accD, 0, 0, 0);
        __asm__ volatile("s_waitcnt lgkmcnt(0)" ::: "memory");
    }

    float tot[4][4], rdv[4];
#pragma unroll
    for (int r = 0; r < 4; ++r) {
        tot[0][r] = acc0[r] + __shfl_xor(acc0[r], 16);
        tot[1][r] = acc1[r] + __shfl_xor(acc1[r], 16);
        tot[2][r] = acc2[r] + __shfl_xor(acc2[r], 16);
        tot[3][r] = acc3[r] + __shfl_xor(acc3[r], 16);
        float d = accD[r] + __shfl_xor(accD[r], 16);
        rdv[r] = 1.f / (d + 1e-16f);
    }
    if (lane < 16) {
        size_t ob = (size_t)node * 256 + lane;
#pragma unroll
        for (int r = 0; r < 4; ++r) {
#pragma unroll
            for (int ct = 0; ct < 4; ++ct)
                aggout[ob + r * 64 + ct * 16] = (_Float16)(tot[ct][r] * rdv[r]);
        }
    }
}

// ---- MLP on matrix cores (unchanged) --------------------------------------

__global__ __launch_bounds__(256) void mlp_mfma(
        const _Float16* __restrict__ agg,
        const _Float16* __restrict__ CP,
        const float* __restrict__ bcomb,
        const float* __restrict__ wc2, const float* __restrict__ bc2,
        int n, float* __restrict__ out) {
    __shared__ float part[4][16][3];
    int tid = threadIdx.x;
    int lane = tid & 63;
    int w = __builtin_amdgcn_readfirstlane(tid >> 6);   // ct slice
    int c16 = lane & 15, hi = lane >> 4;

    f16x8 bh[8], blo[8];
#pragma unroll
    for (int kt = 0; kt < 8; ++kt) {
        bh[kt]  = *(const f16x8*)(CP + (size_t)(w * 8 + kt) * 512 + lane * 8);
        blo[kt] = *(const f16x8*)(CP + (size_t)(32 + w * 8 + kt) * 512 + lane * 8);
    }
    int col = w * 16 + c16;
    float bc  = bcomb[col];
    float w20 = wc2[col * 3 + 0], w21 = wc2[col * 3 + 1], w22 = wc2[col * 3 + 2];
    float bb0 = bc2[0], bb1 = bc2[1], bb2 = bc2[2];

    int ntiles = (n + 15) >> 4;
    for (int tile = blockIdx.x; tile < ntiles; tile += gridDim.x) {
        int rowb = tile * 16;
        int row = min(rowb + c16, n - 1);
        const _Float16* ap = agg + (size_t)row * 256 + hi * 8;
        f16x8 a[8];
#pragma unroll
        for (int kt = 0; kt < 8; ++kt) a[kt] = *(const f16x8*)(ap + kt * 32);
        f32x4 acc = {0.f, 0.f, 0.f, 0.f};
#pragma unroll
        for (int kt = 0; kt < 8; ++kt) {
            acc = __builtin_amdgcn_mfma_f32_16x16x32_f16(a[kt], bh[kt],  acc, 0, 0, 0);
            acc = __builtin_amdgcn_mfma_f32_16x16x32_f16(a[kt], blo[kt], acc, 0, 0, 0);
        }
        float pr[4][3];
#pragma unroll
        for (int r = 0; r < 4; ++r) {
            float z = fmaxf(acc[r] + bc, 0.f);
            pr[r][0] = red16(z * w20);
            pr[r][1] = red16(z * w21);
            pr[r][2] = red16(z * w22);
        }
        if (c16 == 0) {
#pragma unroll
            for (int r = 0; r < 4; ++r) {
                part[w][hi * 4 + r][0] = pr[r][0];
                part[w][hi * 4 + r][1] = pr[r][1];
                part[w][hi * 4 + r][2] = pr[r][2];
            }
        }
        __syncthreads();
        if (tid < 16) {
            int node = rowb + tid;
            if (node < n) {
                float e0 = part[0][tid][0] + part[1][tid][0] + part[2][tid][0] + part[3][tid][0] + bb0;
                float e1 = part[0][tid][1] + part[1][tid][1] + part[2][tid][1] + part[3][tid][1] + bb1;
                float e2 = part[0][tid][2] + part[1][tid][2] + part[2][tid][2] + part[3][tid][2] + bb2;
                float mx = fmaxf(e0, fmaxf(e1, e2));
                float lse = mx + logf(expf(e0 - mx) + expf(e1 - mx) + expf(e2 - mx));
                out[(size_t)node * 3 + 0] = e0 - lse;
                out[(size_t)node * 3 + 1] = e1 - lse;
                out[(size_t)node * 3 + 2] = e2 - lse;
            }
        }
        __syncthreads();
    }
}

// ---------------------------------------------------------------------------

extern "C" void kernel_launch(void* const* d_in, const int* in_sizes, int n_in,
                              void* d_out, int out_size, void* d_ws, size_t ws_size,
                              hipStream_t stream) {
    const float* x       = (const float*)d_in[0];
    const int*   ei      = (const int*)d_in[1];
    const float* w1      = (const float*)d_in[2];
    const float* b1      = (const float*)d_in[3];
    const float* w2      = (const float*)d_in[4];
    const float* b2      = (const float*)d_in[5];
    const float* w3      = (const float*)d_in[6];
    const float* b3      = (const float*)d_in[7];
    const float* wg      = (const float*)d_in[8];
    const float* bg      = (const float*)d_in[9];
    const float* att_s   = (const float*)d_in[10];
    const float* att_d   = (const float*)d_in[11];
    const float* wc1     = (const float*)d_in[12];
    const float* bc1     = (const float*)d_in[13];
    const float* wc2     = (const float*)d_in[14];
    const float* bc2     = (const float*)d_in[15];
    float* out = (float*)d_out;

    const int N = in_sizes[0] / 8;
    const int E = in_sizes[1] / 2;
    const int* srcv = ei;
    const int* dstv = ei + E;

    char* ws = (char*)d_ws;
    size_t off = 0;
    auto alloc = [&](size_t bytes) -> char* {
        char* p = ws + off;
        off += (bytes + 255) & ~(size_t)255;
        return p;
    };
    int*      counts    = (int*)alloc((size_t)N * 4);
    int*      row_ptr   = (int*)alloc((size_t)(N + 1) * 4);
    int*      cursor    = (int*)alloc((size_t)N * 4);
    int*      col_src   = (int*)alloc((size_t)E * 4);
    int*      blockSums = (int*)alloc(4096 * 4);
    int*      blockOffs = (int*)alloc(4096 * 4);
    float*    dinv      = (float*)alloc((size_t)N * 4);
    float*    rdinv     = (float*)alloc((size_t)N * 4);
    _Float16* xs        = (_Float16*)alloc((size_t)N * 8 * 2);
    float*    a_src     = (float*)alloc((size_t)N * 16);
    float*    a_dst     = (float*)alloc((size_t)N * 16);
    float*    wse       = (float*)alloc(256 * 4);
    float*    wde       = (float*)alloc(256 * 4);
    _Float16* CcombP    = (_Float16*)alloc(64 * 1024);           // fp16 hi+lo B-frags
    float*    bcomb     = (float*)alloc(64 * 4);
    _Float16* W2P       = (_Float16*)alloc(16 * 1024);           // gcn W frags
    _Float16* W3P       = (_Float16*)alloc(16 * 1024);
    int*      shortList = (int*)alloc((size_t)N * 4);
    int*      longList  = (int*)alloc((size_t)N * 4);
    int*      nodeCnts  = (int*)alloc(256);
    _Float16* bufA      = (_Float16*)alloc((size_t)N * 64 * 2);  // hs1, later h3
    _Float16* bufB      = (_Float16*)alloc((size_t)N * 64 * 2);  // hs2
    _Float16* aggbuf    = (_Float16*)alloc((size_t)N * 256 * 2); // 51.2MB fp16
    _Float16* hs1 = bufA;
    _Float16* hs2 = bufB;
    _Float16* h3  = bufA;   // hs1 dead once layer3 runs
    _Float16* aggA = aggbuf; // gcn agg rows alias aggbuf (dead until gat_agg)
    (void)ws_size; (void)n_in; (void)out_size;

    hipMemsetAsync(counts, 0, (size_t)N * 4, stream);
    hipMemsetAsync(nodeCnts, 0, 8, stream);

    const int TPB = 256;
    int range = (N + 7) / 8;
    count_kernel<<<1024, TPB, 0, stream>>>(dstv, E, range, counts);

    int NB = (N + 2047) / 2048;
    scan_pass1<<<NB, TPB, 0, stream>>>(counts, N, blockSums);
    scan_pass2<<<1, 64, 0, stream>>>(blockSums, NB, blockOffs);
    scan_pass3<<<NB, TPB, 0, stream>>>(counts, N, blockOffs, x,
                                       row_ptr, cursor, dinv, rdinv, xs,
                                       shortList, longList, nodeCnts);
    scatter_kernel<<<2048, TPB, 0, stream>>>(srcv, dstv, E, range, cursor, col_src);

    ccomb_kernel<<<385, 64, 0, stream>>>(wg, bg, wc1, bc1, att_s, att_d, w2, w3,
                                         CcombP, bcomb, wse, wde, W2P, W3P);

    int gridN = (N + 3) / 4;
    gcn_layer1<<<gridN, TPB, 0, stream>>>((const half8*)xs, w1, b1, row_ptr, col_src,
                                          dinv, N, hs1);

    gcn_agg<<<gridN, TPB, 0, stream>>>(hs1, row_ptr, col_src, dinv, N, aggA);
    gcn_mfma<false><<<2048, TPB, 0, stream>>>(aggA, W2P, b2, hs1, dinv, rdinv,
                                              nullptr, nullptr, N, hs2,
                                              nullptr, nullptr);
    gcn_agg<<<gridN, TPB, 0, stream>>>(hs2, row_ptr, col_src, dinv, N, aggA);
    gcn_mfma<true><<<2048, TPB, 0, stream>>>(aggA, W3P, b3, hs2, dinv, rdinv,
                                             wse, wde, N, h3,
                                             (float4*)a_src, (float4*)a_dst);

    int gridS = ((N + 1) / 2 + 3) / 4;   // worst case all-short
    gat_agg_short<<<gridS, TPB, 0, stream>>>(h3, (const float4*)a_src,
                                             (const float4*)a_dst, row_ptr, col_src,
                                             shortList, nodeCnts, aggbuf);
    gat_agg_long<<<gridN, TPB, 0, stream>>>(h3, (const float4*)a_src,
                                            (const float4*)a_dst, row_ptr, col_src,
                                            longList, nodeCnts, aggbuf);
    mlp_mfma<<<2048, TPB, 0, stream>>>(aggbuf, CcombP, bcomb, wc2, bc2, N, out);
}